// Round 8
// baseline (427.585 us; speedup 1.0000x reference)
//
#include <hip/hip_runtime.h>
#include <cstddef>
#include <cstdint>

#define T_SEQ 100
#define GQ    4      // independent element-groups interleaved per wave

typedef __attribute__((ext_vector_type(8))) short bfrag;
typedef __attribute__((ext_vector_type(4))) float f4;

union FragU { uint32_t u[4]; bfrag v; };

__device__ __forceinline__ float fast_tanh(float x) {
    float e = __expf(2.0f * x);
    float r = __builtin_amdgcn_rcpf(e + 1.0f);
    return 1.0f - 2.0f * r;
}

__device__ __forceinline__ float exp2_fast(float x) {
#if __has_builtin(__builtin_amdgcn_exp2f)
    return __builtin_amdgcn_exp2f(x);
#else
    return __expf(x * 0.6931471805599453f);
#endif
}

// tanh(o)*scale = scale - 2*scale / (2^(o*2*log2e) + 1)
__device__ __forceinline__ float tanh_mul(float o, float scale, float s2) {
    float rr = __builtin_amdgcn_rcpf(exp2_fast(o * 2.8853900817779268f) + 1.0f);
    return fmaf(-s2, rr, scale);
}

#if __has_builtin(__builtin_amdgcn_cvt_pk_bf16_f32)
typedef __attribute__((ext_vector_type(2))) __bf16 bf16x2;
__device__ __forceinline__ void pack8(const float a[8], bfrag& out) {
    FragU O;
    #pragma unroll
    for (int q = 0; q < 4; ++q) {
        bf16x2 p = __builtin_amdgcn_cvt_pk_bf16_f32(a[2 * q], a[2 * q + 1]);
        O.u[q] = __builtin_bit_cast(uint32_t, p);
    }
    out = O.v;
}
#else
__device__ __forceinline__ uint32_t bf16rne(float f) {
    uint32_t u = __float_as_uint(f);
    return (u + 0x7FFFu + ((u >> 16) & 1u)) >> 16;
}
__device__ __forceinline__ void pack8(const float a[8], bfrag& out) {
    FragU O;
    #pragma unroll
    for (int q = 0; q < 4; ++q)
        O.u[q] = bf16rne(a[2 * q]) | (bf16rne(a[2 * q + 1]) << 16);
    out = O.v;
}
#endif

// hi/lo split (fallback fused kernel only)
__device__ __forceinline__ void split8(const float a[8], bfrag& hi, bfrag& lo) {
    FragU H, L;
    #pragma unroll
    for (int q = 0; q < 4; ++q) {
        uint32_t u0 = __float_as_uint(a[2*q]);
        uint32_t u1 = __float_as_uint(a[2*q+1]);
        uint32_t h0 = u0 & 0xFFFF0000u;
        uint32_t h1 = u1 & 0xFFFF0000u;
        H.u[q] = (h0 >> 16) | h1;
        float l0 = a[2*q]     - __uint_as_float(h0);
        float l1 = a[2*q + 1] - __uint_as_float(h1);
        L.u[q] = (__float_as_uint(l0) >> 16) | (__float_as_uint(l1) & 0xFFFF0000u);
    }
    hi = H.v; lo = L.v;
}

__device__ __forceinline__ f4 mfma_(bfrag a, bfrag b, f4 c) {
    return __builtin_amdgcn_mfma_f32_16x16x32_bf16(a, b, c, 0, 0, 0);
}

// ============================================================================
// Main serial kernel: one wave = GQ*16 = 64 elements as 4 interleaved register
// groups sharing one set of single-bf16 weight fragments. RK2 midpoint.
// z(t) stored packed-bf16 to zws; mu computed by the parallel mu_kernel.
// ============================================================================
__global__ __launch_bounds__(64, 1)
void latode_serial4(const float* __restrict__ dt,  const float* __restrict__ x,
                    const float* __restrict__ We1, const float* __restrict__ be1,
                    const float* __restrict__ We2, const float* __restrict__ be2,
                    const float* __restrict__ Wf1, const float* __restrict__ bf1,
                    const float* __restrict__ Wf2, const float* __restrict__ bf2,
                    uint32_t* __restrict__ zws, int B)
{
    const int l = threadIdx.x;
    const int g = l >> 4;
    const int m = l & 15;
    const int js0 = 8 * (m >> 2) + (m & 3);
    const int js1 = js0 + 4;

    float tmp[8];
    bfrag A0, A1, X0, X1, W0, W1;   // single RNE-bf16 weight fragments

    #pragma unroll
    for (int jj = 0; jj < 8; ++jj) {
        int sig = 16 * (jj >> 2) + 4 * g + (jj & 3);
        tmp[jj] = (js0 < 20) ? Wf1[sig * 20 + js0] : 0.0f;
    }
    pack8(tmp, A0);
    #pragma unroll
    for (int jj = 0; jj < 8; ++jj) {
        int sig = 16 * (jj >> 2) + 4 * g + (jj & 3);
        tmp[jj] = (js1 < 20) ? Wf1[sig * 20 + js1] : 0.0f;
    }
    pack8(tmp, A1);
    #pragma unroll
    for (int jj = 0; jj < 8; ++jj) {
        int kx = 8 * g + jj;
        tmp[jj] = (js0 < 20) ? Wf1[(32 + kx) * 20 + js0] : 0.0f;
    }
    pack8(tmp, X0);
    #pragma unroll
    for (int jj = 0; jj < 8; ++jj) {
        int kx = 8 * g + jj;
        tmp[jj] = (js1 < 20) ? Wf1[(32 + kx) * 20 + js1] : 0.0f;
    }
    pack8(tmp, X1);
    #pragma unroll
    for (int jj = 0; jj < 8; ++jj) {
        int j = 8 * g + jj;
        tmp[jj] = (j < 20) ? Wf2[j * 32 + m] : 0.0f;
    }
    pack8(tmp, W0);
    #pragma unroll
    for (int jj = 0; jj < 8; ++jj) {
        int j = 8 * g + jj;
        tmp[jj] = (j < 20) ? Wf2[j * 32 + 16 + m] : 0.0f;
    }
    pack8(tmp, W1);

    f4 bias0, bias1, cb0, cb1;
    #pragma unroll
    for (int r = 0; r < 4; ++r) {
        bias0[r] = bf2[4 * g + r];
        bias1[r] = bf2[16 + 4 * g + r];
        int j0 = 8 * g + r;     cb0[r] = (j0 < 20) ? bf1[j0] : 0.0f;
        int j1 = 8 * g + r + 4; cb1[r] = (j1 < 20) ? bf1[j1] : 0.0f;
    }

    const uint32_t ebase = blockIdx.x * 64 + m;
    uint32_t xoff[GQ], dofs[GQ], zbase[GQ];
    #pragma unroll
    for (int q = 0; q < GQ; ++q) {
        uint32_t e = ebase + 16 * q;
        xoff[q]  = e * (T_SEQ * 32);
        dofs[q]  = e * (T_SEQ * 2);
        zbase[q] = e * (T_SEQ * 16);
    }

    // ---- z0 encode per group (scalar fp32, exact; once) ----
    float z[GQ][8];
    #pragma unroll
    for (int q = 0; q < GQ; ++q) {
        const float* xe = x + xoff[q];
        float x0v[32];
        #pragma unroll
        for (int i = 0; i < 32; i += 4) {
            float4 v = *(const float4*)(xe + i);
            x0v[i] = v.x; x0v[i+1] = v.y; x0v[i+2] = v.z; x0v[i+3] = v.w;
        }
        float h10[10];
        #pragma unroll
        for (int r = 0; r < 10; ++r) {
            float s = be1[r];
            #pragma unroll
            for (int i = 0; i < 32; ++i) s += x0v[i] * We1[i * 10 + r];
            h10[r] = fast_tanh(s);
        }
        #pragma unroll
        for (int jj = 0; jj < 8; ++jj) {
            int sig = 16 * (jj >> 2) + 4 * g + (jj & 3);
            float s = be2[sig];
            #pragma unroll
            for (int r = 0; r < 10; ++r) s += h10[r] * We2[r * 32 + sig];
            z[q][jj] = fast_tanh(s);
        }
    }

    // ---- t=0 cx per group ----
    f4 cx0[GQ], cx1[GQ];
    float scale[GQ];
    #pragma unroll
    for (int q = 0; q < GQ; ++q) {
        const float* xe = x + xoff[q];
        float4 va = *(const float4*)(xe + 8 * g);
        float4 vb = *(const float4*)(xe + 8 * g + 4);
        float2 dd = *(const float2*)(dt + dofs[q]);
        float xt[8] = { va.x, va.y, va.z, va.w, vb.x, vb.y, vb.z, vb.w };
        bfrag xf; pack8(xt, xf);
        cx0[q] = mfma_(X0, xf, cb0);
        cx1[q] = mfma_(X1, xf, cb1);
        scale[q] = (dd.y - dd.x) * 0.01f;
    }

    // f(a) for all groups, interleaved (independent chains fill each other's
    // MFMA/VALU latency).
    auto feval_all = [&](const float (*a)[8], float (*kk)[8]) {
        bfrag bb[GQ];
        #pragma unroll
        for (int q = 0; q < GQ; ++q) pack8(a[q], bb[q]);
        f4 p0[GQ], p1[GQ];
        #pragma unroll
        for (int q = 0; q < GQ; ++q) {
            p0[q] = mfma_(A0, bb[q], cx0[q]);
            p1[q] = mfma_(A1, bb[q], cx1[q]);
        }
        bfrag pf[GQ];
        #pragma unroll
        for (int q = 0; q < GQ; ++q) {
            float pr[8];
            #pragma unroll
            for (int r = 0; r < 4; ++r) {
                pr[r]     = fmaxf(p0[q][r], 0.0f);
                pr[4 + r] = fmaxf(p1[q][r], 0.0f);
            }
            pack8(pr, pf[q]);
        }
        f4 o0[GQ], o1[GQ];
        #pragma unroll
        for (int q = 0; q < GQ; ++q) {
            o0[q] = mfma_(W0, pf[q], bias0);
            o1[q] = mfma_(W1, pf[q], bias1);
        }
        #pragma unroll
        for (int q = 0; q < GQ; ++q) {
            float sc = scale[q], s2 = sc + sc;
            #pragma unroll
            for (int r = 0; r < 4; ++r) {
                kk[q][r]     = tanh_mul(o0[q][r], sc, s2);
                kk[q][4 + r] = tanh_mul(o1[q][r], sc, s2);
            }
        }
    };

    #pragma unroll 1
    for (int t = 0; t < T_SEQ; ++t) {
        // Prefetch t+1 (clamped) — retires during RK work below.
        int tn = (t + 1 < T_SEQ) ? (t + 1) : t;
        float4 na[GQ], nb[GQ];
        float2 nd[GQ];
        #pragma unroll
        for (int q = 0; q < GQ; ++q) {
            const float* xr = x + xoff[q] + tn * 32 + 8 * g;
            na[q] = *(const float4*)(xr);
            nb[q] = *(const float4*)(xr + 4);
            nd[q] = *(const float2*)(dt + dofs[q] + 2 * tn);
        }

        // RK2 midpoint, h = 1: z += f(z + 0.5*f(z))
        float karr[GQ][8], aa[GQ][8];
        feval_all(z, karr);
        #pragma unroll
        for (int q = 0; q < GQ; ++q)
            #pragma unroll
            for (int c = 0; c < 8; ++c) aa[q][c] = fmaf(0.5f, karr[q][c], z[q][c]);
        feval_all(aa, karr);
        #pragma unroll
        for (int q = 0; q < GQ; ++q)
            #pragma unroll
            for (int c = 0; c < 8; ++c) z[q][c] += karr[q][c];

        // Store z(t) packed bf16 (fire-and-forget).
        #pragma unroll
        for (int q = 0; q < GQ; ++q) {
            bfrag zf; pack8(z[q], zf);
            FragU P; P.v = zf;
            uint32_t* rowp = zws + zbase[q] + (uint32_t)t * 16;
            *(uint2*)(rowp + 2 * g)     = make_uint2(P.u[0], P.u[1]);
            *(uint2*)(rowp + 8 + 2 * g) = make_uint2(P.u[2], P.u[3]);
        }

        // cx(t+1) from prefetched x/dt.
        #pragma unroll
        for (int q = 0; q < GQ; ++q) {
            float xt[8] = { na[q].x, na[q].y, na[q].z, na[q].w,
                            nb[q].x, nb[q].y, nb[q].z, nb[q].w };
            bfrag xf; pack8(xt, xf);
            cx0[q] = mfma_(X0, xf, cb0);
            cx1[q] = mfma_(X1, xf, cb1);
            scale[q] = (nd[q].y - nd[q].x) * 0.01f;
        }
    }
}

// Parallel mu head: one thread per (e,t) row.
__global__ __launch_bounds__(256, 4)
void mu_kernel(const uint32_t* __restrict__ zws,
               const float* __restrict__ Wm1, const float* __restrict__ bm1,
               const float* __restrict__ Wm2, const float* __restrict__ bm2,
               float* __restrict__ out, int nrows)
{
    int row = blockIdx.x * 256 + threadIdx.x;
    if (row >= nrows) return;
    const uint4* zp = (const uint4*)(zws + (size_t)row * 16);
    uint4 q0 = zp[0], q1 = zp[1], q2 = zp[2], q3 = zp[3];
    uint32_t du[16] = { q0.x, q0.y, q0.z, q0.w, q1.x, q1.y, q1.z, q1.w,
                        q2.x, q2.y, q2.z, q2.w, q3.x, q3.y, q3.z, q3.w };
    float zf[32];
    #pragma unroll
    for (int d = 0; d < 16; ++d) {
        uint32_t u = du[d];
        zf[2 * d]     = __uint_as_float(u << 16);
        zf[2 * d + 1] = __uint_as_float(u & 0xFFFF0000u);
    }
    float v[10];
    #pragma unroll
    for (int r = 0; r < 10; ++r) v[r] = bm1[r];
    #pragma unroll
    for (int i = 0; i < 32; ++i) {
        float zi = zf[i];
        #pragma unroll
        for (int r = 0; r < 10; ++r) v[r] = fmaf(zi, Wm1[i * 10 + r], v[r]);
    }
    float mu = bm2[0];
    #pragma unroll
    for (int r = 0; r < 10; ++r) mu += fast_tanh(v[r]) * Wm2[r];
    out[row] = mu;
}

// ============================================================================
// Fallback: fused G=1 kernel (round-7 style) if ws too small / B not /64.
// ============================================================================
__global__ __launch_bounds__(64, 1)
void latode_fused(const float* __restrict__ dt,  const float* __restrict__ x,
                  const float* __restrict__ We1, const float* __restrict__ be1,
                  const float* __restrict__ We2, const float* __restrict__ be2,
                  const float* __restrict__ Wf1, const float* __restrict__ bf1,
                  const float* __restrict__ Wf2, const float* __restrict__ bf2,
                  const float* __restrict__ Wm1, const float* __restrict__ bm1,
                  const float* __restrict__ Wm2, const float* __restrict__ bm2,
                  float* __restrict__ out, int B)
{
    const int l = threadIdx.x;
    const int g = l >> 4;
    const int m = l & 15;
    const int e = blockIdx.x * 16 + m;
    if (e >= B) return;
    const int js0 = 8 * (m >> 2) + (m & 3);
    const int js1 = js0 + 4;

    float tmp[8];
    bfrag A0h, A0l, A1h, A1l, X0h, X0l, X1h, X1l, W0h, W0l, W1h, W1l, Mh, Ml;
    #pragma unroll
    for (int jj = 0; jj < 8; ++jj) {
        int sig = 16 * (jj >> 2) + 4 * g + (jj & 3);
        tmp[jj] = (js0 < 20) ? Wf1[sig * 20 + js0] : 0.0f;
    }
    split8(tmp, A0h, A0l);
    #pragma unroll
    for (int jj = 0; jj < 8; ++jj) {
        int sig = 16 * (jj >> 2) + 4 * g + (jj & 3);
        tmp[jj] = (js1 < 20) ? Wf1[sig * 20 + js1] : 0.0f;
    }
    split8(tmp, A1h, A1l);
    #pragma unroll
    for (int jj = 0; jj < 8; ++jj) {
        int kx = 8 * g + jj;
        tmp[jj] = (js0 < 20) ? Wf1[(32 + kx) * 20 + js0] : 0.0f;
    }
    split8(tmp, X0h, X0l);
    #pragma unroll
    for (int jj = 0; jj < 8; ++jj) {
        int kx = 8 * g + jj;
        tmp[jj] = (js1 < 20) ? Wf1[(32 + kx) * 20 + js1] : 0.0f;
    }
    split8(tmp, X1h, X1l);
    #pragma unroll
    for (int jj = 0; jj < 8; ++jj) {
        int j = 8 * g + jj;
        tmp[jj] = (j < 20) ? Wf2[j * 32 + m] : 0.0f;
    }
    split8(tmp, W0h, W0l);
    #pragma unroll
    for (int jj = 0; jj < 8; ++jj) {
        int j = 8 * g + jj;
        tmp[jj] = (j < 20) ? Wf2[j * 32 + 16 + m] : 0.0f;
    }
    split8(tmp, W1h, W1l);
    #pragma unroll
    for (int jj = 0; jj < 8; ++jj) {
        int sig = 16 * (jj >> 2) + 4 * g + (jj & 3);
        tmp[jj] = (m < 10) ? Wm1[sig * 10 + m] : 0.0f;
    }
    split8(tmp, Mh, Ml);

    f4 bias0, bias1, cb0, cb1, bmv;
    float wm2r[4];
    #pragma unroll
    for (int r = 0; r < 4; ++r) {
        bias0[r] = bf2[4 * g + r];
        bias1[r] = bf2[16 + 4 * g + r];
        int j0 = 8 * g + r;     cb0[r] = (j0 < 20) ? bf1[j0] : 0.0f;
        int j1 = 8 * g + r + 4; cb1[r] = (j1 < 20) ? bf1[j1] : 0.0f;
        int vr = 4 * g + r;
        bmv[r]  = (vr < 10) ? bm1[vr] : 0.0f;
        wm2r[r] = (vr < 10) ? Wm2[vr] : 0.0f;
    }

    const float* xe  = x  + (size_t)e * T_SEQ * 32;
    const float* dte = dt + (size_t)e * T_SEQ * 2;

    float z[8];
    {
        float x0v[32];
        #pragma unroll
        for (int i = 0; i < 32; i += 4) {
            float4 v = *(const float4*)(xe + i);
            x0v[i] = v.x; x0v[i+1] = v.y; x0v[i+2] = v.z; x0v[i+3] = v.w;
        }
        float h10[10];
        #pragma unroll
        for (int r = 0; r < 10; ++r) {
            float s = be1[r];
            #pragma unroll
            for (int i = 0; i < 32; ++i) s += x0v[i] * We1[i * 10 + r];
            h10[r] = fast_tanh(s);
        }
        #pragma unroll
        for (int jj = 0; jj < 8; ++jj) {
            int sig = 16 * (jj >> 2) + 4 * g + (jj & 3);
            float s = be2[sig];
            #pragma unroll
            for (int r = 0; r < 10; ++r) s += h10[r] * We2[r * 32 + sig];
            z[jj] = fast_tanh(s);
        }
    }

    const float bm2s = bm2[0];
    f4 cx0, cx1;
    float scale;
    {
        float4 va = *(const float4*)(xe + 8 * g);
        float4 vb = *(const float4*)(xe + 8 * g + 4);
        float2 dd = *(const float2*)(dte);
        float xt[8] = { va.x, va.y, va.z, va.w, vb.x, vb.y, vb.z, vb.w };
        bfrag xf; pack8(xt, xf);
        cx0 = mfma_(X0h, xf, mfma_(X0l, xf, cb0));
        cx1 = mfma_(X1h, xf, mfma_(X1l, xf, cb1));
        scale = (dd.y - dd.x) * 0.01f;
    }

    for (int t = 0; t < T_SEQ; ++t) {
        int tn = (t + 1 < T_SEQ) ? (t + 1) : t;
        const float* xr = xe + tn * 32 + 8 * g;
        float4 na = *(const float4*)(xr);
        float4 nb = *(const float4*)(xr + 4);
        float2 nd = *(const float2*)(dte + 2 * tn);
        const float s2 = scale + scale;

        auto feval = [&](const float a[8], float kk[8]) {
            bfrag bb; pack8(a, bb);
            f4 p0 = mfma_(A0h, bb, mfma_(A0l, bb, cx0));
            f4 p1 = mfma_(A1h, bb, mfma_(A1l, bb, cx1));
            float pr[8];
            #pragma unroll
            for (int r = 0; r < 4; ++r) {
                pr[r]     = fmaxf(p0[r], 0.0f);
                pr[4 + r] = fmaxf(p1[r], 0.0f);
            }
            bfrag pf; pack8(pr, pf);
            f4 o0 = mfma_(W0h, pf, mfma_(W0l, pf, bias0));
            f4 o1 = mfma_(W1h, pf, mfma_(W1l, pf, bias1));
            #pragma unroll
            for (int r = 0; r < 4; ++r) {
                kk[r]     = tanh_mul(o0[r], scale, s2);
                kk[4 + r] = tanh_mul(o1[r], scale, s2);
            }
        };

        float k[8], arg[8];
        feval(z, k);
        #pragma unroll
        for (int c = 0; c < 8; ++c) arg[c] = fmaf(0.5f, k[c], z[c]);
        feval(arg, k);
        #pragma unroll
        for (int c = 0; c < 8; ++c) z[c] += k[c];

        {
            float xt[8] = { na.x, na.y, na.z, na.w, nb.x, nb.y, nb.z, nb.w };
            bfrag xf; pack8(xt, xf);
            cx0 = mfma_(X0h, xf, mfma_(X0l, xf, cb0));
            cx1 = mfma_(X1h, xf, mfma_(X1l, xf, cb1));
            scale = (nd.y - nd.x) * 0.01f;
        }

        bfrag zh, zl; split8(z, zh, zl);
        f4 vv = mfma_(Mh, zh, mfma_(Mh, zl, mfma_(Ml, zh, bmv)));
        float p = 0.0f;
        #pragma unroll
        for (int r = 0; r < 4; ++r) p += fast_tanh(vv[r]) * wm2r[r];
        p += __shfl_xor(p, 16, 64);
        p += __shfl_xor(p, 32, 64);
        if (l < 16) out[(size_t)e * T_SEQ + t] = p + bm2s;
    }
}

extern "C" void kernel_launch(void* const* d_in, const int* in_sizes, int n_in,
                              void* d_out, int out_size, void* d_ws, size_t ws_size,
                              hipStream_t stream) {
    const float* dt  = (const float*)d_in[0];
    const float* x   = (const float*)d_in[1];
    const float* We1 = (const float*)d_in[2];
    const float* be1 = (const float*)d_in[3];
    const float* We2 = (const float*)d_in[4];
    const float* be2 = (const float*)d_in[5];
    const float* Wf1 = (const float*)d_in[6];
    const float* bf1 = (const float*)d_in[7];
    const float* Wf2 = (const float*)d_in[8];
    const float* bf2 = (const float*)d_in[9];
    const float* Wm1 = (const float*)d_in[10];
    const float* bm1 = (const float*)d_in[11];
    const float* Wm2 = (const float*)d_in[12];
    const float* bm2 = (const float*)d_in[13];
    float* out = (float*)d_out;

    const int B = in_sizes[0] / (T_SEQ * 2);   // 8192
    const size_t zbytes = (size_t)B * T_SEQ * 32 * 2;

    if (ws_size >= zbytes && (B % 64) == 0) {
        hipLaunchKernelGGL(latode_serial4, dim3(B / 64), dim3(64), 0, stream,
                           dt, x, We1, be1, We2, be2, Wf1, bf1, Wf2, bf2,
                           (uint32_t*)d_ws, B);
        int nrows = B * T_SEQ;
        hipLaunchKernelGGL(mu_kernel, dim3((nrows + 255) / 256), dim3(256), 0, stream,
                           (const uint32_t*)d_ws, Wm1, bm1, Wm2, bm2, out, nrows);
    } else {
        hipLaunchKernelGGL(latode_fused, dim3((B + 15) / 16), dim3(64), 0, stream,
                           dt, x, We1, be1, We2, be2, Wf1, bf1, Wf2, bf2,
                           Wm1, bm1, Wm2, bm2, out, B);
    }
}

// Round 9
// 264.914 us; speedup vs baseline: 1.6141x; 1.6141x over previous
//
#include <hip/hip_runtime.h>
#include <cstddef>
#include <cstdint>

#define T_SEQ 100

typedef __attribute__((ext_vector_type(8))) short bfrag;
typedef __attribute__((ext_vector_type(4))) float f4;

union FragU { uint32_t u[4]; bfrag v; };

__device__ __forceinline__ float fast_tanh(float x) {
    float e = __expf(2.0f * x);
    float r = __builtin_amdgcn_rcpf(e + 1.0f);
    return 1.0f - 2.0f * r;
}

__device__ __forceinline__ float exp2_fast(float x) {
#if __has_builtin(__builtin_amdgcn_exp2f)
    return __builtin_amdgcn_exp2f(x);
#else
    return __expf(x * 0.6931471805599453f);
#endif
}

// tanh(o)*scale = scale - 2*scale / (2^(o*2*log2e) + 1)
__device__ __forceinline__ float tanh_mul(float o, float scale, float s2) {
    float rr = __builtin_amdgcn_rcpf(exp2_fast(o * 2.8853900817779268f) + 1.0f);
    return fmaf(-s2, rr, scale);
}

#if __has_builtin(__builtin_amdgcn_cvt_pk_bf16_f32)
typedef __attribute__((ext_vector_type(2))) __bf16 bf16x2;
__device__ __forceinline__ void pack8(const float a[8], bfrag& out) {
    FragU O;
    #pragma unroll
    for (int q = 0; q < 4; ++q) {
        bf16x2 p = __builtin_amdgcn_cvt_pk_bf16_f32(a[2 * q], a[2 * q + 1]);
        O.u[q] = __builtin_bit_cast(uint32_t, p);
    }
    out = O.v;
}
#else
__device__ __forceinline__ uint32_t bf16rne(float f) {
    uint32_t u = __float_as_uint(f);
    return (u + 0x7FFFu + ((u >> 16) & 1u)) >> 16;
}
__device__ __forceinline__ void pack8(const float a[8], bfrag& out) {
    FragU O;
    #pragma unroll
    for (int q = 0; q < 4; ++q)
        O.u[q] = bf16rne(a[2 * q]) | (bf16rne(a[2 * q + 1]) << 16);
    out = O.v;
}
#endif

__device__ __forceinline__ f4 mfma_(bfrag a, bfrag b, f4 c) {
    return __builtin_amdgcn_mfma_f32_16x16x32_bf16(a, b, c, 0, 0, 0);
}

// ============================================================================
// Serial recurrence: one wave = 16 elements, Euler step (1 feval per t).
// Error model: |g|<=0.01, J~0.002 -> Euler LTE ~2e-6/step; RK4 n=8->1 was
// bit-identical (absmax pinned at the 2^-11 output rounding floor), so the
// integrator slack is >100x. Weights = single RNE-bf16 fragments (validated
// round 8: absmax unchanged). z(t) stored packed-bf16; mu in parallel kernel.
// ============================================================================
__global__ __launch_bounds__(64, 1)
void latode_serial(const float* __restrict__ dt,  const float* __restrict__ x,
                   const float* __restrict__ We1, const float* __restrict__ be1,
                   const float* __restrict__ We2, const float* __restrict__ be2,
                   const float* __restrict__ Wf1, const float* __restrict__ bf1,
                   const float* __restrict__ Wf2, const float* __restrict__ bf2,
                   uint32_t* __restrict__ zws, int B)
{
    const int l = threadIdx.x;
    const int g = l >> 4;
    const int m = l & 15;
    const int e = blockIdx.x * 16 + m;
    const int js0 = 8 * (m >> 2) + (m & 3);
    const int js1 = js0 + 4;

    float tmp[8];
    bfrag A0, A1, X0, X1, W0, W1;   // single RNE-bf16 weight fragments

    #pragma unroll
    for (int jj = 0; jj < 8; ++jj) {
        int sig = 16 * (jj >> 2) + 4 * g + (jj & 3);
        tmp[jj] = (js0 < 20) ? Wf1[sig * 20 + js0] : 0.0f;
    }
    pack8(tmp, A0);
    #pragma unroll
    for (int jj = 0; jj < 8; ++jj) {
        int sig = 16 * (jj >> 2) + 4 * g + (jj & 3);
        tmp[jj] = (js1 < 20) ? Wf1[sig * 20 + js1] : 0.0f;
    }
    pack8(tmp, A1);
    #pragma unroll
    for (int jj = 0; jj < 8; ++jj) {
        int kx = 8 * g + jj;
        tmp[jj] = (js0 < 20) ? Wf1[(32 + kx) * 20 + js0] : 0.0f;
    }
    pack8(tmp, X0);
    #pragma unroll
    for (int jj = 0; jj < 8; ++jj) {
        int kx = 8 * g + jj;
        tmp[jj] = (js1 < 20) ? Wf1[(32 + kx) * 20 + js1] : 0.0f;
    }
    pack8(tmp, X1);
    #pragma unroll
    for (int jj = 0; jj < 8; ++jj) {
        int j = 8 * g + jj;
        tmp[jj] = (j < 20) ? Wf2[j * 32 + m] : 0.0f;
    }
    pack8(tmp, W0);
    #pragma unroll
    for (int jj = 0; jj < 8; ++jj) {
        int j = 8 * g + jj;
        tmp[jj] = (j < 20) ? Wf2[j * 32 + 16 + m] : 0.0f;
    }
    pack8(tmp, W1);

    f4 bias0, bias1, cb0, cb1;
    #pragma unroll
    for (int r = 0; r < 4; ++r) {
        bias0[r] = bf2[4 * g + r];
        bias1[r] = bf2[16 + 4 * g + r];
        int j0 = 8 * g + r;     cb0[r] = (j0 < 20) ? bf1[j0] : 0.0f;
        int j1 = 8 * g + r + 4; cb1[r] = (j1 < 20) ? bf1[j1] : 0.0f;
    }

    const float* xe  = x  + (size_t)e * T_SEQ * 32;
    const float* dte = dt + (size_t)e * T_SEQ * 2;
    uint32_t* zrow = zws + (size_t)e * T_SEQ * 16;

    // ---- z0 encode (scalar fp32, once) ----
    float z[8];
    {
        float x0v[32];
        #pragma unroll
        for (int i = 0; i < 32; i += 4) {
            float4 v = *(const float4*)(xe + i);
            x0v[i] = v.x; x0v[i+1] = v.y; x0v[i+2] = v.z; x0v[i+3] = v.w;
        }
        float h10[10];
        #pragma unroll
        for (int r = 0; r < 10; ++r) {
            float s = be1[r];
            #pragma unroll
            for (int i = 0; i < 32; ++i) s += x0v[i] * We1[i * 10 + r];
            h10[r] = fast_tanh(s);
        }
        #pragma unroll
        for (int jj = 0; jj < 8; ++jj) {
            int sig = 16 * (jj >> 2) + 4 * g + (jj & 3);
            float s = be2[sig];
            #pragma unroll
            for (int r = 0; r < 10; ++r) s += h10[r] * We2[r * 32 + sig];
            z[jj] = fast_tanh(s);
        }
    }

    // ---- t=0 cx (cx for t computed at the end of iteration t-1) ----
    f4 cx0, cx1;
    float scale;
    {
        float4 va = *(const float4*)(xe + 8 * g);
        float4 vb = *(const float4*)(xe + 8 * g + 4);
        float2 dd = *(const float2*)(dte);
        float xt[8] = { va.x, va.y, va.z, va.w, vb.x, vb.y, vb.z, vb.w };
        bfrag xf; pack8(xt, xf);
        cx0 = mfma_(X0, xf, cb0);
        cx1 = mfma_(X1, xf, cb1);
        scale = (dd.y - dd.x) * 0.01f;
    }

    #pragma unroll 1
    for (int t = 0; t < T_SEQ; ++t) {
        // Prefetch t+1 (clamped); retires during the feval below.
        int tn = (t + 1 < T_SEQ) ? (t + 1) : t;
        const float* xr = xe + tn * 32 + 8 * g;
        float4 na = *(const float4*)(xr);
        float4 nb = *(const float4*)(xr + 4);
        float2 nd = *(const float2*)(dte + 2 * tn);

        const float s2 = scale + scale;

        // ---- Euler: z += f(z) ----
        bfrag bb; pack8(z, bb);
        f4 p0 = mfma_(A0, bb, cx0);
        f4 p1 = mfma_(A1, bb, cx1);
        float pr[8];
        #pragma unroll
        for (int r = 0; r < 4; ++r) {
            pr[r]     = fmaxf(p0[r], 0.0f);
            pr[4 + r] = fmaxf(p1[r], 0.0f);
        }
        bfrag pf; pack8(pr, pf);
        f4 o0 = mfma_(W0, pf, bias0);
        f4 o1 = mfma_(W1, pf, bias1);
        #pragma unroll
        for (int r = 0; r < 4; ++r) {
            z[r]     += tanh_mul(o0[r], scale, s2);
            z[4 + r] += tanh_mul(o1[r], scale, s2);
        }

        // Store z(t) packed bf16 (fire-and-forget).
        {
            bfrag zf; pack8(z, zf);
            FragU P; P.v = zf;
            uint32_t* rowp = zrow + (uint32_t)t * 16;
            *(uint2*)(rowp + 2 * g)     = make_uint2(P.u[0], P.u[1]);
            *(uint2*)(rowp + 8 + 2 * g) = make_uint2(P.u[2], P.u[3]);
        }

        // cx(t+1) from prefetched x/dt (off the z-chain).
        {
            float xt[8] = { na.x, na.y, na.z, na.w, nb.x, nb.y, nb.z, nb.w };
            bfrag xf; pack8(xt, xf);
            cx0 = mfma_(X0, xf, cb0);
            cx1 = mfma_(X1, xf, cb1);
            scale = (nd.y - nd.x) * 0.01f;
        }
    }
}

// Parallel mu head: one thread per (e,t) row.
__global__ __launch_bounds__(256, 4)
void mu_kernel(const uint32_t* __restrict__ zws,
               const float* __restrict__ Wm1, const float* __restrict__ bm1,
               const float* __restrict__ Wm2, const float* __restrict__ bm2,
               float* __restrict__ out, int nrows)
{
    int row = blockIdx.x * 256 + threadIdx.x;
    if (row >= nrows) return;
    const uint4* zp = (const uint4*)(zws + (size_t)row * 16);
    uint4 q0 = zp[0], q1 = zp[1], q2 = zp[2], q3 = zp[3];
    uint32_t du[16] = { q0.x, q0.y, q0.z, q0.w, q1.x, q1.y, q1.z, q1.w,
                        q2.x, q2.y, q2.z, q2.w, q3.x, q3.y, q3.z, q3.w };
    float zf[32];
    #pragma unroll
    for (int d = 0; d < 16; ++d) {
        uint32_t u = du[d];
        zf[2 * d]     = __uint_as_float(u << 16);
        zf[2 * d + 1] = __uint_as_float(u & 0xFFFF0000u);
    }
    float v[10];
    #pragma unroll
    for (int r = 0; r < 10; ++r) v[r] = bm1[r];
    #pragma unroll
    for (int i = 0; i < 32; ++i) {
        float zi = zf[i];
        #pragma unroll
        for (int r = 0; r < 10; ++r) v[r] = fmaf(zi, Wm1[i * 10 + r], v[r]);
    }
    float mu = bm2[0];
    #pragma unroll
    for (int r = 0; r < 10; ++r) mu += fast_tanh(v[r]) * Wm2[r];
    out[row] = mu;
}

// ============================================================================
// Fallback (ws too small / B not /16): fused Euler, mu in-loop.
// ============================================================================
__global__ __launch_bounds__(64, 1)
void latode_fused(const float* __restrict__ dt,  const float* __restrict__ x,
                  const float* __restrict__ We1, const float* __restrict__ be1,
                  const float* __restrict__ We2, const float* __restrict__ be2,
                  const float* __restrict__ Wf1, const float* __restrict__ bf1,
                  const float* __restrict__ Wf2, const float* __restrict__ bf2,
                  const float* __restrict__ Wm1, const float* __restrict__ bm1,
                  const float* __restrict__ Wm2, const float* __restrict__ bm2,
                  float* __restrict__ out, int B)
{
    const int l = threadIdx.x;
    const int g = l >> 4;
    const int m = l & 15;
    const int e = blockIdx.x * 16 + m;
    if (e >= B) return;
    const int js0 = 8 * (m >> 2) + (m & 3);
    const int js1 = js0 + 4;

    float tmp[8];
    bfrag A0, A1, X0, X1, W0, W1, M0;
    #pragma unroll
    for (int jj = 0; jj < 8; ++jj) {
        int sig = 16 * (jj >> 2) + 4 * g + (jj & 3);
        tmp[jj] = (js0 < 20) ? Wf1[sig * 20 + js0] : 0.0f;
    }
    pack8(tmp, A0);
    #pragma unroll
    for (int jj = 0; jj < 8; ++jj) {
        int sig = 16 * (jj >> 2) + 4 * g + (jj & 3);
        tmp[jj] = (js1 < 20) ? Wf1[sig * 20 + js1] : 0.0f;
    }
    pack8(tmp, A1);
    #pragma unroll
    for (int jj = 0; jj < 8; ++jj) {
        int kx = 8 * g + jj;
        tmp[jj] = (js0 < 20) ? Wf1[(32 + kx) * 20 + js0] : 0.0f;
    }
    pack8(tmp, X0);
    #pragma unroll
    for (int jj = 0; jj < 8; ++jj) {
        int kx = 8 * g + jj;
        tmp[jj] = (js1 < 20) ? Wf1[(32 + kx) * 20 + js1] : 0.0f;
    }
    pack8(tmp, X1);
    #pragma unroll
    for (int jj = 0; jj < 8; ++jj) {
        int j = 8 * g + jj;
        tmp[jj] = (j < 20) ? Wf2[j * 32 + m] : 0.0f;
    }
    pack8(tmp, W0);
    #pragma unroll
    for (int jj = 0; jj < 8; ++jj) {
        int j = 8 * g + jj;
        tmp[jj] = (j < 20) ? Wf2[j * 32 + 16 + m] : 0.0f;
    }
    pack8(tmp, W1);
    #pragma unroll
    for (int jj = 0; jj < 8; ++jj) {
        int sig = 16 * (jj >> 2) + 4 * g + (jj & 3);
        tmp[jj] = (m < 10) ? Wm1[sig * 10 + m] : 0.0f;
    }
    pack8(tmp, M0);

    f4 bias0, bias1, cb0, cb1, bmv;
    float wm2r[4];
    #pragma unroll
    for (int r = 0; r < 4; ++r) {
        bias0[r] = bf2[4 * g + r];
        bias1[r] = bf2[16 + 4 * g + r];
        int j0 = 8 * g + r;     cb0[r] = (j0 < 20) ? bf1[j0] : 0.0f;
        int j1 = 8 * g + r + 4; cb1[r] = (j1 < 20) ? bf1[j1] : 0.0f;
        int vr = 4 * g + r;
        bmv[r]  = (vr < 10) ? bm1[vr] : 0.0f;
        wm2r[r] = (vr < 10) ? Wm2[vr] : 0.0f;
    }

    const float* xe  = x  + (size_t)e * T_SEQ * 32;
    const float* dte = dt + (size_t)e * T_SEQ * 2;

    float z[8];
    {
        float x0v[32];
        #pragma unroll
        for (int i = 0; i < 32; i += 4) {
            float4 v = *(const float4*)(xe + i);
            x0v[i] = v.x; x0v[i+1] = v.y; x0v[i+2] = v.z; x0v[i+3] = v.w;
        }
        float h10[10];
        #pragma unroll
        for (int r = 0; r < 10; ++r) {
            float s = be1[r];
            #pragma unroll
            for (int i = 0; i < 32; ++i) s += x0v[i] * We1[i * 10 + r];
            h10[r] = fast_tanh(s);
        }
        #pragma unroll
        for (int jj = 0; jj < 8; ++jj) {
            int sig = 16 * (jj >> 2) + 4 * g + (jj & 3);
            float s = be2[sig];
            #pragma unroll
            for (int r = 0; r < 10; ++r) s += h10[r] * We2[r * 32 + sig];
            z[jj] = fast_tanh(s);
        }
    }

    const float bm2s = bm2[0];
    f4 cx0, cx1;
    float scale;
    {
        float4 va = *(const float4*)(xe + 8 * g);
        float4 vb = *(const float4*)(xe + 8 * g + 4);
        float2 dd = *(const float2*)(dte);
        float xt[8] = { va.x, va.y, va.z, va.w, vb.x, vb.y, vb.z, vb.w };
        bfrag xf; pack8(xt, xf);
        cx0 = mfma_(X0, xf, cb0);
        cx1 = mfma_(X1, xf, cb1);
        scale = (dd.y - dd.x) * 0.01f;
    }

    for (int t = 0; t < T_SEQ; ++t) {
        int tn = (t + 1 < T_SEQ) ? (t + 1) : t;
        const float* xr = xe + tn * 32 + 8 * g;
        float4 na = *(const float4*)(xr);
        float4 nb = *(const float4*)(xr + 4);
        float2 nd = *(const float2*)(dte + 2 * tn);
        const float s2 = scale + scale;

        bfrag bb; pack8(z, bb);
        f4 p0 = mfma_(A0, bb, cx0);
        f4 p1 = mfma_(A1, bb, cx1);
        float pr[8];
        #pragma unroll
        for (int r = 0; r < 4; ++r) {
            pr[r]     = fmaxf(p0[r], 0.0f);
            pr[4 + r] = fmaxf(p1[r], 0.0f);
        }
        bfrag pf; pack8(pr, pf);
        f4 o0 = mfma_(W0, pf, bias0);
        f4 o1 = mfma_(W1, pf, bias1);
        #pragma unroll
        for (int r = 0; r < 4; ++r) {
            z[r]     += tanh_mul(o0[r], scale, s2);
            z[4 + r] += tanh_mul(o1[r], scale, s2);
        }

        {
            float xt[8] = { na.x, na.y, na.z, na.w, nb.x, nb.y, nb.z, nb.w };
            bfrag xf; pack8(xt, xf);
            cx0 = mfma_(X0, xf, cb0);
            cx1 = mfma_(X1, xf, cb1);
            scale = (nd.y - nd.x) * 0.01f;
        }

        bfrag zf; pack8(z, zf);
        f4 vv = mfma_(M0, zf, bmv);
        float p = 0.0f;
        #pragma unroll
        for (int r = 0; r < 4; ++r) p += fast_tanh(vv[r]) * wm2r[r];
        p += __shfl_xor(p, 16, 64);
        p += __shfl_xor(p, 32, 64);
        if (l < 16) out[(size_t)e * T_SEQ + t] = p + bm2s;
    }
}

extern "C" void kernel_launch(void* const* d_in, const int* in_sizes, int n_in,
                              void* d_out, int out_size, void* d_ws, size_t ws_size,
                              hipStream_t stream) {
    const float* dt  = (const float*)d_in[0];
    const float* x   = (const float*)d_in[1];
    const float* We1 = (const float*)d_in[2];
    const float* be1 = (const float*)d_in[3];
    const float* We2 = (const float*)d_in[4];
    const float* be2 = (const float*)d_in[5];
    const float* Wf1 = (const float*)d_in[6];
    const float* bf1 = (const float*)d_in[7];
    const float* Wf2 = (const float*)d_in[8];
    const float* bf2 = (const float*)d_in[9];
    const float* Wm1 = (const float*)d_in[10];
    const float* bm1 = (const float*)d_in[11];
    const float* Wm2 = (const float*)d_in[12];
    const float* bm2 = (const float*)d_in[13];
    float* out = (float*)d_out;

    const int B = in_sizes[0] / (T_SEQ * 2);   // 8192
    const size_t zbytes = (size_t)B * T_SEQ * 32 * 2;

    if (ws_size >= zbytes && (B % 16) == 0) {
        hipLaunchKernelGGL(latode_serial, dim3(B / 16), dim3(64), 0, stream,
                           dt, x, We1, be1, We2, be2, Wf1, bf1, Wf2, bf2,
                           (uint32_t*)d_ws, B);
        int nrows = B * T_SEQ;
        hipLaunchKernelGGL(mu_kernel, dim3((nrows + 255) / 256), dim3(256), 0, stream,
                           (const uint32_t*)d_ws, Wm1, bm1, Wm2, bm2, out, nrows);
    } else {
        hipLaunchKernelGGL(latode_fused, dim3((B + 15) / 16), dim3(64), 0, stream,
                           dt, x, We1, be1, We2, be2, Wf1, bf1, Wf2, bf2,
                           Wm1, bm1, Wm2, bm2, out, B);
    }
}

// Round 10
// 228.094 us; speedup vs baseline: 1.8746x; 1.1614x over previous
//
#include <hip/hip_runtime.h>
#include <cstddef>
#include <cstdint>

#define T_SEQ 100

typedef __attribute__((ext_vector_type(8))) short bfrag;
typedef __attribute__((ext_vector_type(4))) float f4;

union FragU { uint32_t u[4]; bfrag v; };

__device__ __forceinline__ float fast_tanh(float x) {
    float e = __expf(2.0f * x);
    float r = __builtin_amdgcn_rcpf(e + 1.0f);
    return 1.0f - 2.0f * r;
}

__device__ __forceinline__ float exp2_fast(float x) {
#if __has_builtin(__builtin_amdgcn_exp2f)
    return __builtin_amdgcn_exp2f(x);
#else
    return __expf(x * 0.6931471805599453f);
#endif
}

// tanh(o)*scale = scale - 2*scale / (2^(o*2*log2e) + 1)
__device__ __forceinline__ float tanh_mul(float o, float scale, float s2) {
    float rr = __builtin_amdgcn_rcpf(exp2_fast(o * 2.8853900817779268f) + 1.0f);
    return fmaf(-s2, rr, scale);
}

#if __has_builtin(__builtin_amdgcn_cvt_pk_bf16_f32)
typedef __attribute__((ext_vector_type(2))) __bf16 bf16x2;
__device__ __forceinline__ void pack8(const float a[8], bfrag& out) {
    FragU O;
    #pragma unroll
    for (int q = 0; q < 4; ++q) {
        bf16x2 p = __builtin_amdgcn_cvt_pk_bf16_f32(a[2 * q], a[2 * q + 1]);
        O.u[q] = __builtin_bit_cast(uint32_t, p);
    }
    out = O.v;
}
#else
__device__ __forceinline__ uint32_t bf16rne(float f) {
    uint32_t u = __float_as_uint(f);
    return (u + 0x7FFFu + ((u >> 16) & 1u)) >> 16;
}
__device__ __forceinline__ void pack8(const float a[8], bfrag& out) {
    FragU O;
    #pragma unroll
    for (int q = 0; q < 4; ++q)
        O.u[q] = bf16rne(a[2 * q]) | (bf16rne(a[2 * q + 1]) << 16);
    out = O.v;
}
#endif

__device__ __forceinline__ f4 mfma_(bfrag a, bfrag b, f4 c) {
    return __builtin_amdgcn_mfma_f32_16x16x32_bf16(a, b, c, 0, 0, 0);
}

// ============================================================================
// Serial recurrence: one wave = 16 elements, Euler step (1 feval/t), 2-deep
// software-pipelined x/dt prefetch (loads issued ~1.8 iterations before use —
// r9's per-t cost was dominated by exposed HBM latency, not the feval chain).
// z(t) stored packed-bf16 to zws; mu computed by the parallel mu_kernel.
// ============================================================================
__global__ __launch_bounds__(64, 1)
void latode_serial(const float* __restrict__ dt,  const float* __restrict__ x,
                   const float* __restrict__ We1, const float* __restrict__ be1,
                   const float* __restrict__ We2, const float* __restrict__ be2,
                   const float* __restrict__ Wf1, const float* __restrict__ bf1,
                   const float* __restrict__ Wf2, const float* __restrict__ bf2,
                   uint32_t* __restrict__ zws, int B)
{
    const int l = threadIdx.x;
    const int g = l >> 4;
    const int m = l & 15;
    const int e = blockIdx.x * 16 + m;
    const int js0 = 8 * (m >> 2) + (m & 3);
    const int js1 = js0 + 4;

    float tmp[8];
    bfrag A0, A1, X0, X1, W0, W1;   // single RNE-bf16 weight fragments

    #pragma unroll
    for (int jj = 0; jj < 8; ++jj) {
        int sig = 16 * (jj >> 2) + 4 * g + (jj & 3);
        tmp[jj] = (js0 < 20) ? Wf1[sig * 20 + js0] : 0.0f;
    }
    pack8(tmp, A0);
    #pragma unroll
    for (int jj = 0; jj < 8; ++jj) {
        int sig = 16 * (jj >> 2) + 4 * g + (jj & 3);
        tmp[jj] = (js1 < 20) ? Wf1[sig * 20 + js1] : 0.0f;
    }
    pack8(tmp, A1);
    #pragma unroll
    for (int jj = 0; jj < 8; ++jj) {
        int kx = 8 * g + jj;
        tmp[jj] = (js0 < 20) ? Wf1[(32 + kx) * 20 + js0] : 0.0f;
    }
    pack8(tmp, X0);
    #pragma unroll
    for (int jj = 0; jj < 8; ++jj) {
        int kx = 8 * g + jj;
        tmp[jj] = (js1 < 20) ? Wf1[(32 + kx) * 20 + js1] : 0.0f;
    }
    pack8(tmp, X1);
    #pragma unroll
    for (int jj = 0; jj < 8; ++jj) {
        int j = 8 * g + jj;
        tmp[jj] = (j < 20) ? Wf2[j * 32 + m] : 0.0f;
    }
    pack8(tmp, W0);
    #pragma unroll
    for (int jj = 0; jj < 8; ++jj) {
        int j = 8 * g + jj;
        tmp[jj] = (j < 20) ? Wf2[j * 32 + 16 + m] : 0.0f;
    }
    pack8(tmp, W1);

    f4 bias0, bias1, cb0, cb1;
    #pragma unroll
    for (int r = 0; r < 4; ++r) {
        bias0[r] = bf2[4 * g + r];
        bias1[r] = bf2[16 + 4 * g + r];
        int j0 = 8 * g + r;     cb0[r] = (j0 < 20) ? bf1[j0] : 0.0f;
        int j1 = 8 * g + r + 4; cb1[r] = (j1 < 20) ? bf1[j1] : 0.0f;
    }

    const float* xe  = x  + (size_t)e * T_SEQ * 32;
    const float* xp  = xe + 8 * g;
    const float* dte = dt + (size_t)e * T_SEQ * 2;
    uint32_t* zrow = zws + (size_t)e * T_SEQ * 16;

    // ---- z0 encode (scalar fp32, once) ----
    float z[8];
    {
        float x0v[32];
        #pragma unroll
        for (int i = 0; i < 32; i += 4) {
            float4 v = *(const float4*)(xe + i);
            x0v[i] = v.x; x0v[i+1] = v.y; x0v[i+2] = v.z; x0v[i+3] = v.w;
        }
        float h10[10];
        #pragma unroll
        for (int r = 0; r < 10; ++r) {
            float s = be1[r];
            #pragma unroll
            for (int i = 0; i < 32; ++i) s += x0v[i] * We1[i * 10 + r];
            h10[r] = fast_tanh(s);
        }
        #pragma unroll
        for (int jj = 0; jj < 8; ++jj) {
            int sig = 16 * (jj >> 2) + 4 * g + (jj & 3);
            float s = be2[sig];
            #pragma unroll
            for (int r = 0; r < 10; ++r) s += h10[r] * We2[r * 32 + sig];
            z[jj] = fast_tanh(s);
        }
    }

    struct XBuf { float4 a, b; float2 d; };
    auto load_into = [&](XBuf& Bf, int t) {
        const float* xr = xp + (size_t)t * 32;
        Bf.a = *(const float4*)(xr);
        Bf.b = *(const float4*)(xr + 4);
        Bf.d = *(const float2*)(dte + 2 * t);
    };
    auto cx_from = [&](const XBuf& Bf, f4& c0, f4& c1, float& sc) {
        float xt[8] = { Bf.a.x, Bf.a.y, Bf.a.z, Bf.a.w,
                        Bf.b.x, Bf.b.y, Bf.b.z, Bf.b.w };
        bfrag xf; pack8(xt, xf);
        c0 = mfma_(X0, xf, cb0);
        c1 = mfma_(X1, xf, cb1);
        sc = (Bf.d.y - Bf.d.x) * 0.01f;
    };

    // ---- pipeline preamble ----
    f4 cx0, cx1;
    float scale;
    XBuf Bn, Bf2;
    {
        XBuf Bc; load_into(Bc, 0);
        cx_from(Bc, cx0, cx1, scale);   // cx for t=0
    }
    load_into(Bn, 1);                   // data for t=1 (in flight across t=0 body)

    // One Euler sub-step body: feval(z) with current cx/scale, update z, store.
    auto body = [&](int t) {
        const float s2 = scale + scale;
        bfrag bb; pack8(z, bb);
        f4 p0 = mfma_(A0, bb, cx0);
        f4 p1 = mfma_(A1, bb, cx1);
        float pr[8];
        #pragma unroll
        for (int r = 0; r < 4; ++r) {
            pr[r]     = fmaxf(p0[r], 0.0f);
            pr[4 + r] = fmaxf(p1[r], 0.0f);
        }
        bfrag pf; pack8(pr, pf);
        f4 o0 = mfma_(W0, pf, bias0);
        f4 o1 = mfma_(W1, pf, bias1);
        #pragma unroll
        for (int r = 0; r < 4; ++r) {
            z[r]     += tanh_mul(o0[r], scale, s2);
            z[4 + r] += tanh_mul(o1[r], scale, s2);
        }
        bfrag zf; pack8(z, zf);
        FragU P; P.v = zf;
        uint32_t* rowp = zrow + (uint32_t)t * 16;
        *(uint2*)(rowp + 2 * g)     = make_uint2(P.u[0], P.u[1]);
        *(uint2*)(rowp + 8 + 2 * g) = make_uint2(P.u[2], P.u[3]);
    };

    #pragma unroll 1
    for (int t = 0; t < T_SEQ; t += 2) {
        // --- sub-iter t: Bn holds t+1 (arrived); prefetch t+2 into Bf2 ---
        {
            int tf = (t + 2 < T_SEQ) ? (t + 2) : (T_SEQ - 1);
            load_into(Bf2, tf);
        }
        body(t);
        cx_from(Bn, cx0, cx1, scale);       // cx for t+1 (data loaded 2 bodies ago)

        // --- sub-iter t+1: Bf2 holds t+2; prefetch t+3 into Bn ---
        {
            int tf = (t + 3 < T_SEQ) ? (t + 3) : (T_SEQ - 1);
            load_into(Bn, tf);
        }
        body(t + 1);
        cx_from(Bf2, cx0, cx1, scale);      // cx for t+2
    }
}

// Parallel mu head: one thread per (e,t) row.
__global__ __launch_bounds__(256, 4)
void mu_kernel(const uint32_t* __restrict__ zws,
               const float* __restrict__ Wm1, const float* __restrict__ bm1,
               const float* __restrict__ Wm2, const float* __restrict__ bm2,
               float* __restrict__ out, int nrows)
{
    int row = blockIdx.x * 256 + threadIdx.x;
    if (row >= nrows) return;
    const uint4* zp = (const uint4*)(zws + (size_t)row * 16);
    uint4 q0 = zp[0], q1 = zp[1], q2 = zp[2], q3 = zp[3];
    uint32_t du[16] = { q0.x, q0.y, q0.z, q0.w, q1.x, q1.y, q1.z, q1.w,
                        q2.x, q2.y, q2.z, q2.w, q3.x, q3.y, q3.z, q3.w };
    float zf[32];
    #pragma unroll
    for (int d = 0; d < 16; ++d) {
        uint32_t u = du[d];
        zf[2 * d]     = __uint_as_float(u << 16);
        zf[2 * d + 1] = __uint_as_float(u & 0xFFFF0000u);
    }
    float v[10];
    #pragma unroll
    for (int r = 0; r < 10; ++r) v[r] = bm1[r];
    #pragma unroll
    for (int i = 0; i < 32; ++i) {
        float zi = zf[i];
        #pragma unroll
        for (int r = 0; r < 10; ++r) v[r] = fmaf(zi, Wm1[i * 10 + r], v[r]);
    }
    float mu = bm2[0];
    #pragma unroll
    for (int r = 0; r < 10; ++r) mu += fast_tanh(v[r]) * Wm2[r];
    out[row] = mu;
}

// ============================================================================
// Fallback (ws too small / B not /16): fused Euler, mu in-loop.
// ============================================================================
__global__ __launch_bounds__(64, 1)
void latode_fused(const float* __restrict__ dt,  const float* __restrict__ x,
                  const float* __restrict__ We1, const float* __restrict__ be1,
                  const float* __restrict__ We2, const float* __restrict__ be2,
                  const float* __restrict__ Wf1, const float* __restrict__ bf1,
                  const float* __restrict__ Wf2, const float* __restrict__ bf2,
                  const float* __restrict__ Wm1, const float* __restrict__ bm1,
                  const float* __restrict__ Wm2, const float* __restrict__ bm2,
                  float* __restrict__ out, int B)
{
    const int l = threadIdx.x;
    const int g = l >> 4;
    const int m = l & 15;
    const int e = blockIdx.x * 16 + m;
    if (e >= B) return;
    const int js0 = 8 * (m >> 2) + (m & 3);
    const int js1 = js0 + 4;

    float tmp[8];
    bfrag A0, A1, X0, X1, W0, W1, M0;
    #pragma unroll
    for (int jj = 0; jj < 8; ++jj) {
        int sig = 16 * (jj >> 2) + 4 * g + (jj & 3);
        tmp[jj] = (js0 < 20) ? Wf1[sig * 20 + js0] : 0.0f;
    }
    pack8(tmp, A0);
    #pragma unroll
    for (int jj = 0; jj < 8; ++jj) {
        int sig = 16 * (jj >> 2) + 4 * g + (jj & 3);
        tmp[jj] = (js1 < 20) ? Wf1[sig * 20 + js1] : 0.0f;
    }
    pack8(tmp, A1);
    #pragma unroll
    for (int jj = 0; jj < 8; ++jj) {
        int kx = 8 * g + jj;
        tmp[jj] = (js0 < 20) ? Wf1[(32 + kx) * 20 + js0] : 0.0f;
    }
    pack8(tmp, X0);
    #pragma unroll
    for (int jj = 0; jj < 8; ++jj) {
        int kx = 8 * g + jj;
        tmp[jj] = (js1 < 20) ? Wf1[(32 + kx) * 20 + js1] : 0.0f;
    }
    pack8(tmp, X1);
    #pragma unroll
    for (int jj = 0; jj < 8; ++jj) {
        int j = 8 * g + jj;
        tmp[jj] = (j < 20) ? Wf2[j * 32 + m] : 0.0f;
    }
    pack8(tmp, W0);
    #pragma unroll
    for (int jj = 0; jj < 8; ++jj) {
        int j = 8 * g + jj;
        tmp[jj] = (j < 20) ? Wf2[j * 32 + 16 + m] : 0.0f;
    }
    pack8(tmp, W1);
    #pragma unroll
    for (int jj = 0; jj < 8; ++jj) {
        int sig = 16 * (jj >> 2) + 4 * g + (jj & 3);
        tmp[jj] = (m < 10) ? Wm1[sig * 10 + m] : 0.0f;
    }
    pack8(tmp, M0);

    f4 bias0, bias1, cb0, cb1, bmv;
    float wm2r[4];
    #pragma unroll
    for (int r = 0; r < 4; ++r) {
        bias0[r] = bf2[4 * g + r];
        bias1[r] = bf2[16 + 4 * g + r];
        int j0 = 8 * g + r;     cb0[r] = (j0 < 20) ? bf1[j0] : 0.0f;
        int j1 = 8 * g + r + 4; cb1[r] = (j1 < 20) ? bf1[j1] : 0.0f;
        int vr = 4 * g + r;
        bmv[r]  = (vr < 10) ? bm1[vr] : 0.0f;
        wm2r[r] = (vr < 10) ? Wm2[vr] : 0.0f;
    }

    const float* xe  = x  + (size_t)e * T_SEQ * 32;
    const float* dte = dt + (size_t)e * T_SEQ * 2;

    float z[8];
    {
        float x0v[32];
        #pragma unroll
        for (int i = 0; i < 32; i += 4) {
            float4 v = *(const float4*)(xe + i);
            x0v[i] = v.x; x0v[i+1] = v.y; x0v[i+2] = v.z; x0v[i+3] = v.w;
        }
        float h10[10];
        #pragma unroll
        for (int r = 0; r < 10; ++r) {
            float s = be1[r];
            #pragma unroll
            for (int i = 0; i < 32; ++i) s += x0v[i] * We1[i * 10 + r];
            h10[r] = fast_tanh(s);
        }
        #pragma unroll
        for (int jj = 0; jj < 8; ++jj) {
            int sig = 16 * (jj >> 2) + 4 * g + (jj & 3);
            float s = be2[sig];
            #pragma unroll
            for (int r = 0; r < 10; ++r) s += h10[r] * We2[r * 32 + sig];
            z[jj] = fast_tanh(s);
        }
    }

    const float bm2s = bm2[0];
    f4 cx0, cx1;
    float scale;
    {
        float4 va = *(const float4*)(xe + 8 * g);
        float4 vb = *(const float4*)(xe + 8 * g + 4);
        float2 dd = *(const float2*)(dte);
        float xt[8] = { va.x, va.y, va.z, va.w, vb.x, vb.y, vb.z, vb.w };
        bfrag xf; pack8(xt, xf);
        cx0 = mfma_(X0, xf, cb0);
        cx1 = mfma_(X1, xf, cb1);
        scale = (dd.y - dd.x) * 0.01f;
    }

    for (int t = 0; t < T_SEQ; ++t) {
        int tn = (t + 1 < T_SEQ) ? (t + 1) : t;
        const float* xr = xe + tn * 32 + 8 * g;
        float4 na = *(const float4*)(xr);
        float4 nb = *(const float4*)(xr + 4);
        float2 nd = *(const float2*)(dte + 2 * tn);
        const float s2 = scale + scale;

        bfrag bb; pack8(z, bb);
        f4 p0 = mfma_(A0, bb, cx0);
        f4 p1 = mfma_(A1, bb, cx1);
        float pr[8];
        #pragma unroll
        for (int r = 0; r < 4; ++r) {
            pr[r]     = fmaxf(p0[r], 0.0f);
            pr[4 + r] = fmaxf(p1[r], 0.0f);
        }
        bfrag pf; pack8(pr, pf);
        f4 o0 = mfma_(W0, pf, bias0);
        f4 o1 = mfma_(W1, pf, bias1);
        #pragma unroll
        for (int r = 0; r < 4; ++r) {
            z[r]     += tanh_mul(o0[r], scale, s2);
            z[4 + r] += tanh_mul(o1[r], scale, s2);
        }

        {
            float xt[8] = { na.x, na.y, na.z, na.w, nb.x, nb.y, nb.z, nb.w };
            bfrag xf; pack8(xt, xf);
            cx0 = mfma_(X0, xf, cb0);
            cx1 = mfma_(X1, xf, cb1);
            scale = (nd.y - nd.x) * 0.01f;
        }

        bfrag zf; pack8(z, zf);
        f4 vv = mfma_(M0, zf, bmv);
        float p = 0.0f;
        #pragma unroll
        for (int r = 0; r < 4; ++r) p += fast_tanh(vv[r]) * wm2r[r];
        p += __shfl_xor(p, 16, 64);
        p += __shfl_xor(p, 32, 64);
        if (l < 16) out[(size_t)e * T_SEQ + t] = p + bm2s;
    }
}

extern "C" void kernel_launch(void* const* d_in, const int* in_sizes, int n_in,
                              void* d_out, int out_size, void* d_ws, size_t ws_size,
                              hipStream_t stream) {
    const float* dt  = (const float*)d_in[0];
    const float* x   = (const float*)d_in[1];
    const float* We1 = (const float*)d_in[2];
    const float* be1 = (const float*)d_in[3];
    const float* We2 = (const float*)d_in[4];
    const float* be2 = (const float*)d_in[5];
    const float* Wf1 = (const float*)d_in[6];
    const float* bf1 = (const float*)d_in[7];
    const float* Wf2 = (const float*)d_in[8];
    const float* bf2 = (const float*)d_in[9];
    const float* Wm1 = (const float*)d_in[10];
    const float* bm1 = (const float*)d_in[11];
    const float* Wm2 = (const float*)d_in[12];
    const float* bm2 = (const float*)d_in[13];
    float* out = (float*)d_out;

    const int B = in_sizes[0] / (T_SEQ * 2);   // 8192
    const size_t zbytes = (size_t)B * T_SEQ * 32 * 2;

    if (ws_size >= zbytes && (B % 16) == 0) {
        hipLaunchKernelGGL(latode_serial, dim3(B / 16), dim3(64), 0, stream,
                           dt, x, We1, be1, We2, be2, Wf1, bf1, Wf2, bf2,
                           (uint32_t*)d_ws, B);
        int nrows = B * T_SEQ;
        hipLaunchKernelGGL(mu_kernel, dim3((nrows + 255) / 256), dim3(256), 0, stream,
                           (const uint32_t*)d_ws, Wm1, bm1, Wm2, bm2, out, nrows);
    } else {
        hipLaunchKernelGGL(latode_fused, dim3((B + 15) / 16), dim3(64), 0, stream,
                           dt, x, We1, be1, We2, be2, Wf1, bf1, Wf2, bf2,
                           Wm1, bm1, Wm2, bm2, out, B);
    }
}